// Round 1
// baseline (485.387 us; speedup 1.0000x reference)
//
#include <hip/hip_runtime.h>
#include <math.h>

#define NPTS 2000000
#define GG 32
#define FF 5
#define BLK 256

__global__ __launch_bounds__(256, 8) void hashgrid_kernel(
    const float* __restrict__ x,
    const float* __restrict__ feat,
    const int* __restrict__ btab,
    float* __restrict__ out)
{
    // staging: [0,1280) feats | [1280,5120) dfeats
    // (region [0,768) first reused to stage x coalesced)
    // mask is NOT staged: per-thread dword store is already stride-1 coalesced.
    // LDS = 5120 floats = 20480 B exactly -> 8 blocks/CU (160 KiB), 32 waves/CU.
    __shared__ float smem[5120];
    const int tid  = threadIdx.x;
    const int bid  = blockIdx.x;
    const int base = bid * BLK;
    const int cnt  = min(BLK, NPTS - base);   // 256, or 128 for the last block

    // ---- stage x (coalesced float4) ----
    {
        const float4* xin = (const float4*)(x + (size_t)base * 3);
        float4* s4 = (float4*)smem;
        int nf4 = (cnt * 3) >> 2;             // 192 or 96
        for (int i = tid; i < nf4; i += BLK) s4[i] = xin[i];
    }
    __syncthreads();

    float x0 = 0.f, x1 = 0.f, x2 = 0.f;
    if (tid < cnt) { x0 = smem[tid*3+0]; x1 = smem[tid*3+1]; x2 = smem[tid*3+2]; }
    __syncthreads();   // smem reused for outputs below

    float accf[5] = {0,0,0,0,0};
    float adx[5]  = {0,0,0,0,0};
    float ady[5]  = {0,0,0,0,0};
    float adz[5]  = {0,0,0,0,0};
    float mval = 0.f;

    if (tid < cnt) {
        // reference semantics: u = fl32(x * 100.0f), floor/frac in f32
        float u0 = x0 * 100.0f, u1 = x1 * 100.0f, u2 = x2 * 100.0f;
        float fl0 = floorf(u0), fl1 = floorf(u1), fl2 = floorf(u2);
        int xi0 = (int)fl0, xi1 = (int)fl1, xi2 = (int)fl2;
        float fr0 = u0 - fl0, fr1 = u1 - fl1, fr2 = u2 - fl2;

        int offs[8];
        bool ok = true;
        #pragma unroll
        for (int c = 0; c < 8; ++c) {
            int i = (c >> 2) & 1, j = (c >> 1) & 1, k = c & 1;
            int g0 = xi0 + i, g1 = xi1 + j, g2 = xi2 + k;
            int b0 = g0 >> 3, b1 = g1 >> 3, b2 = g2 >> 3;
            bool inb = ((unsigned)b0 < GG) & ((unsigned)b1 < GG) & ((unsigned)b2 < GG);
            int c0 = min(max(b0,0),GG-1), c1 = min(max(b1,0),GG-1), c2 = min(max(b2,0),GG-1);
            int bidx = btab[(c0 * GG + c1) * GG + c2];
            ok &= inb & (bidx >= 0);
            int vidx = ((g0 & 7) * 8 + (g1 & 7)) * 8 + (g2 & 7);
            offs[c] = max(bidx, 0) * 520 + vidx;
        }

        if (ok) {
            mval = 1.f;
            float p0[2] = {1.f - fr0, fr0};
            float p1[2] = {1.f - fr1, fr1};
            float p2[2] = {1.f - fr2, fr2};
            // vectorized 20B row gather: dwordx4 (align-4, unaligned-mode) + dword
            struct __attribute__((packed, aligned(4))) R16 { float4 v; };
            // Two explicit batches of 4 rows: issue 8 loads, then consume,
            // guaranteeing >=4 rows (8 vmem ops) in flight for latency hiding.
            #pragma unroll
            for (int b = 0; b < 2; ++b) {
                float4 q[4]; float t[4];
                #pragma unroll
                for (int c = 0; c < 4; ++c) {
                    const float* fp = feat + (size_t)offs[b*4 + c] * 5;
                    q[c] = ((const R16*)fp)->v;
                    t[c] = fp[4];
                }
                #pragma unroll
                for (int c = 0; c < 4; ++c) {
                    int cc = b*4 + c;
                    int i = (cc >> 2) & 1, j = (cc >> 1) & 1, k = cc & 1;
                    float wi = p0[i], wj = p1[j], wk = p2[k];
                    float si = i ? 1.f : -1.f;
                    float sj = j ? 1.f : -1.f;
                    float sk = k ? 1.f : -1.f;
                    float w   = wi * wj * wk;
                    float dwx = si * wj * wk;
                    float dwy = wi * sj * wk;
                    float dwz = wi * wj * sk;
                    float vv[5] = {q[c].x, q[c].y, q[c].z, q[c].w, t[c]};
                    #pragma unroll
                    for (int f = 0; f < 5; ++f) {
                        float v = vv[f];
                        accf[f] += w   * v;
                        adx[f]  += dwx * v;
                        ady[f]  += dwy * v;
                        adz[f]  += dwz * v;
                    }
                }
            }
        }
    }

    // ---- stage outputs into LDS (odd strides 5/15 -> near-conflict-free) ----
    if (tid < cnt) {
        float* fs = smem + tid * 5;
        #pragma unroll
        for (int f = 0; f < 5; ++f) fs[f] = accf[f];
        float* ds = smem + 1280 + tid * 15;
        #pragma unroll
        for (int f = 0; f < 5; ++f) {
            ds[f*3+0] = adx[f] * 100.0f;
            ds[f*3+1] = ady[f] * 100.0f;
            ds[f*3+2] = adz[f] * 100.0f;
        }
        // mask: direct coalesced dword store (no staging needed)
        out[(size_t)NPTS * 20 + base + tid] = mval;
    }
    __syncthreads();

    // ---- coalesced float4 global writes ----
    {
        const float4* s4 = (const float4*)smem;
        float4* o = (float4*)(out + (size_t)base * 5);
        int nf4 = (cnt * 5) >> 2;             // 320 or 160
        for (int i = tid; i < nf4; i += BLK) o[i] = s4[i];
    }
    {
        const float4* s4 = (const float4*)(smem + 1280);
        float4* o = (float4*)(out + (size_t)NPTS * 5 + (size_t)base * 15);
        int nf4 = (cnt * 15) >> 2;            // 960 or 480
        for (int i = tid; i < nf4; i += BLK) o[i] = s4[i];
    }
}

extern "C" void kernel_launch(void* const* d_in, const int* in_sizes, int n_in,
                              void* d_out, int out_size, void* d_ws, size_t ws_size,
                              hipStream_t stream) {
    const float* x    = (const float*)d_in[0];
    const float* feat = (const float*)d_in[1];
    const int*   btab = (const int*)d_in[2];
    float* out = (float*)d_out;
    int blocks = (NPTS + BLK - 1) / BLK;      // 7813
    hashgrid_kernel<<<blocks, BLK, 0, stream>>>(x, feat, btab, out);
}

// Round 2
// 469.256 us; speedup vs baseline: 1.0344x; 1.0344x over previous
//
#include <hip/hip_runtime.h>
#include <math.h>

#define NPTS 2000000
#define GG 32
#define FF 5
#define BLK 256

// NOTE: plain __launch_bounds__(256), NOT (256,8).
// r1 evidence: forcing minwaves=8 caps VGPR at 64; the batched gather needs
// ~60-75 live regs, and the allocator spilled to scratch (+85.7 MiB WRITE_SIZE,
// +46 MiB FETCH_SIZE of pure spill traffic, VGPR collapsed to 32). Let the
// allocator float; batch-of-4 rows should land ~56-64 VGPR with no spill.
__global__ __launch_bounds__(256) void hashgrid_kernel(
    const float* __restrict__ x,
    const float* __restrict__ feat,
    const int* __restrict__ btab,
    float* __restrict__ out)
{
    // staging: [0,1280) feats | [1280,5120) dfeats
    // (region [0,768) first reused to stage x coalesced)
    // mask is NOT staged: per-thread dword store is already stride-1 coalesced.
    // LDS = 5120 floats = 20480 B exactly -> 8 blocks/CU fit if VGPR <= 64.
    __shared__ float smem[5120];
    const int tid  = threadIdx.x;
    const int bid  = blockIdx.x;
    const int base = bid * BLK;
    const int cnt  = min(BLK, NPTS - base);   // 256, or 128 for the last block

    // ---- stage x (coalesced float4) ----
    {
        const float4* xin = (const float4*)(x + (size_t)base * 3);
        float4* s4 = (float4*)smem;
        int nf4 = (cnt * 3) >> 2;             // 192 or 96
        for (int i = tid; i < nf4; i += BLK) s4[i] = xin[i];
    }
    __syncthreads();

    float x0 = 0.f, x1 = 0.f, x2 = 0.f;
    if (tid < cnt) { x0 = smem[tid*3+0]; x1 = smem[tid*3+1]; x2 = smem[tid*3+2]; }
    __syncthreads();   // smem reused for outputs below

    float accf[5] = {0,0,0,0,0};
    float adx[5]  = {0,0,0,0,0};
    float ady[5]  = {0,0,0,0,0};
    float adz[5]  = {0,0,0,0,0};
    float mval = 0.f;

    if (tid < cnt) {
        // reference semantics: u = fl32(x * 100.0f), floor/frac in f32
        float u0 = x0 * 100.0f, u1 = x1 * 100.0f, u2 = x2 * 100.0f;
        float fl0 = floorf(u0), fl1 = floorf(u1), fl2 = floorf(u2);
        int xi0 = (int)fl0, xi1 = (int)fl1, xi2 = (int)fl2;
        float fr0 = u0 - fl0, fr1 = u1 - fl1, fr2 = u2 - fl2;

        int offs[8];
        bool ok = true;
        #pragma unroll
        for (int c = 0; c < 8; ++c) {
            int i = (c >> 2) & 1, j = (c >> 1) & 1, k = c & 1;
            int g0 = xi0 + i, g1 = xi1 + j, g2 = xi2 + k;
            int b0 = g0 >> 3, b1 = g1 >> 3, b2 = g2 >> 3;
            bool inb = ((unsigned)b0 < GG) & ((unsigned)b1 < GG) & ((unsigned)b2 < GG);
            int c0 = min(max(b0,0),GG-1), c1 = min(max(b1,0),GG-1), c2 = min(max(b2,0),GG-1);
            int bidx = btab[(c0 * GG + c1) * GG + c2];
            ok &= inb & (bidx >= 0);
            int vidx = ((g0 & 7) * 8 + (g1 & 7)) * 8 + (g2 & 7);
            offs[c] = max(bidx, 0) * 520 + vidx;
        }

        if (ok) {
            mval = 1.f;
            float p0[2] = {1.f - fr0, fr0};
            float p1[2] = {1.f - fr1, fr1};
            float p2[2] = {1.f - fr2, fr2};
            // vectorized 20B row gather: dwordx4 (align-4, unaligned-mode) + dword
            struct __attribute__((packed, aligned(4))) R16 { float4 v; };
            // Two batches of 4 rows: issue 8 loads, then consume.
            // ~20 load regs live per batch; with no launch_bounds VGPR cap the
            // scheduler keeps issue order -> >=8 vmem ops in flight per wave.
            #pragma unroll
            for (int b = 0; b < 2; ++b) {
                float4 q[4]; float t[4];
                #pragma unroll
                for (int c = 0; c < 4; ++c) {
                    const float* fp = feat + (size_t)offs[b*4 + c] * 5;
                    q[c] = ((const R16*)fp)->v;
                    t[c] = fp[4];
                }
                #pragma unroll
                for (int c = 0; c < 4; ++c) {
                    int cc = b*4 + c;
                    int i = (cc >> 2) & 1, j = (cc >> 1) & 1, k = cc & 1;
                    float wi = p0[i], wj = p1[j], wk = p2[k];
                    float si = i ? 1.f : -1.f;
                    float sj = j ? 1.f : -1.f;
                    float sk = k ? 1.f : -1.f;
                    float w   = wi * wj * wk;
                    float dwx = si * wj * wk;
                    float dwy = wi * sj * wk;
                    float dwz = wi * wj * sk;
                    float vv[5] = {q[c].x, q[c].y, q[c].z, q[c].w, t[c]};
                    #pragma unroll
                    for (int f = 0; f < 5; ++f) {
                        float v = vv[f];
                        accf[f] += w   * v;
                        adx[f]  += dwx * v;
                        ady[f]  += dwy * v;
                        adz[f]  += dwz * v;
                    }
                }
            }
        }
    }

    // ---- stage outputs into LDS (odd strides 5/15 -> near-conflict-free) ----
    if (tid < cnt) {
        float* fs = smem + tid * 5;
        #pragma unroll
        for (int f = 0; f < 5; ++f) fs[f] = accf[f];
        float* ds = smem + 1280 + tid * 15;
        #pragma unroll
        for (int f = 0; f < 5; ++f) {
            ds[f*3+0] = adx[f] * 100.0f;
            ds[f*3+1] = ady[f] * 100.0f;
            ds[f*3+2] = adz[f] * 100.0f;
        }
        // mask: direct coalesced dword store (no staging needed)
        out[(size_t)NPTS * 20 + base + tid] = mval;
    }
    __syncthreads();

    // ---- coalesced float4 global writes ----
    {
        const float4* s4 = (const float4*)smem;
        float4* o = (float4*)(out + (size_t)base * 5);
        int nf4 = (cnt * 5) >> 2;             // 320 or 160
        for (int i = tid; i < nf4; i += BLK) o[i] = s4[i];
    }
    {
        const float4* s4 = (const float4*)(smem + 1280);
        float4* o = (float4*)(out + (size_t)NPTS * 5 + (size_t)base * 15);
        int nf4 = (cnt * 15) >> 2;            // 960 or 480
        for (int i = tid; i < nf4; i += BLK) o[i] = s4[i];
    }
}

extern "C" void kernel_launch(void* const* d_in, const int* in_sizes, int n_in,
                              void* d_out, int out_size, void* d_ws, size_t ws_size,
                              hipStream_t stream) {
    const float* x    = (const float*)d_in[0];
    const float* feat = (const float*)d_in[1];
    const int*   btab = (const int*)d_in[2];
    float* out = (float*)d_out;
    int blocks = (NPTS + BLK - 1) / BLK;      // 7813
    hashgrid_kernel<<<blocks, BLK, 0, stream>>>(x, feat, btab, out);
}

// Round 3
// 436.072 us; speedup vs baseline: 1.1131x; 1.0761x over previous
//
#include <hip/hip_runtime.h>
#include <math.h>

#define NPTS 2000000
#define GG 32
#define FF 5
#define BLK 256

typedef float v4f __attribute__((ext_vector_type(4)));

// r1/r2 lesson: hipcc's pressure heuristic sinks gather loads next to their
// uses (VGPR=36, ~1-2 rows in flight) no matter how the C code is batched.
// This version forces the memory pipeline with asm volatile loads + a single
// counted wait tied to the results via "+v" data deps (rule-18 discipline).
__global__ __launch_bounds__(256) void hashgrid_kernel(
    const float* __restrict__ x,
    const float* __restrict__ feat,
    const int* __restrict__ btab,
    float* __restrict__ out)
{
    // staging: [0,1280) feats | [1280,5120) dfeats
    // (region [0,768) first reused to stage x coalesced)
    // mask stored direct (coalesced dword). LDS = 20480 B.
    __shared__ float smem[5120];
    const int tid  = threadIdx.x;
    const int bid  = blockIdx.x;
    const int base = bid * BLK;
    const int cnt  = min(BLK, NPTS - base);   // 256, or 128 for the last block

    // ---- stage x (coalesced float4) ----
    {
        const float4* xin = (const float4*)(x + (size_t)base * 3);
        float4* s4 = (float4*)smem;
        int nf4 = (cnt * 3) >> 2;             // 192 or 96
        for (int i = tid; i < nf4; i += BLK) s4[i] = xin[i];
    }
    __syncthreads();

    float x0 = 0.f, x1 = 0.f, x2 = 0.f;
    if (tid < cnt) { x0 = smem[tid*3+0]; x1 = smem[tid*3+1]; x2 = smem[tid*3+2]; }
    __syncthreads();   // smem reused for outputs below

    float accf[5] = {0,0,0,0,0};
    float adx[5]  = {0,0,0,0,0};
    float ady[5]  = {0,0,0,0,0};
    float adz[5]  = {0,0,0,0,0};
    float mval = 0.f;

    if (tid < cnt) {
        // reference semantics: u = fl32(x * 100.0f), floor/frac in f32
        float u0 = x0 * 100.0f, u1 = x1 * 100.0f, u2 = x2 * 100.0f;
        float fl0 = floorf(u0), fl1 = floorf(u1), fl2 = floorf(u2);
        int xi0 = (int)fl0, xi1 = (int)fl1, xi2 = (int)fl2;
        float fr0 = u0 - fl0, fr1 = u1 - fl1, fr2 = u2 - fl2;

        // ---- phase 1: 8 parallel btab gathers (forced in-flight) ----
        int vidx[8]; bool inb[8]; int bv[8];
        #pragma unroll
        for (int c = 0; c < 8; ++c) {
            int i = (c >> 2) & 1, j = (c >> 1) & 1, k = c & 1;
            int g0 = xi0 + i, g1 = xi1 + j, g2 = xi2 + k;
            int b0 = g0 >> 3, b1 = g1 >> 3, b2 = g2 >> 3;
            inb[c] = ((unsigned)b0 < GG) & ((unsigned)b1 < GG) & ((unsigned)b2 < GG);
            int c0 = min(max(b0,0),GG-1), c1 = min(max(b1,0),GG-1), c2 = min(max(b2,0),GG-1);
            vidx[c] = ((g0 & 7) * 8 + (g1 & 7)) * 8 + (g2 & 7);
            const int* bp = btab + ((c0 * GG + c1) * GG + c2);
            asm volatile("global_load_dword %0, %1, off"
                         : "=v"(bv[c]) : "v"(bp));
        }
        asm volatile("s_waitcnt vmcnt(0)"
                     : "+v"(bv[0]), "+v"(bv[1]), "+v"(bv[2]), "+v"(bv[3]),
                       "+v"(bv[4]), "+v"(bv[5]), "+v"(bv[6]), "+v"(bv[7]));
        __builtin_amdgcn_sched_barrier(0);

        bool ok = true;
        int offs[8];
        #pragma unroll
        for (int c = 0; c < 8; ++c) {
            ok &= inb[c] & (bv[c] >= 0);
            offs[c] = max(bv[c], 0) * 520 + vidx[c];
        }

        if (ok) {
            mval = 1.f;
            float p0[2] = {1.f - fr0, fr0};
            float p1[2] = {1.f - fr1, fr1};
            float p2[2] = {1.f - fr2, fr2};

            // ---- phase 2: 16 parallel feat gathers (forced in-flight) ----
            // 20B row = dwordx4 (align-4, unaligned-mode ok, same inst the
            // compiler emitted in r0) + dword at offset:16 off same address.
            v4f q[8]; float t[8];
            #pragma unroll
            for (int c = 0; c < 8; ++c) {
                const float* fp = feat + (size_t)offs[c] * 5;
                asm volatile("global_load_dwordx4 %0, %1, off"
                             : "=v"(q[c]) : "v"(fp));
                asm volatile("global_load_dword %0, %1, off offset:16"
                             : "=v"(t[c]) : "v"(fp));
            }
            asm volatile("s_waitcnt vmcnt(0)"
                         : "+v"(q[0]), "+v"(q[1]), "+v"(q[2]), "+v"(q[3]),
                           "+v"(q[4]), "+v"(q[5]), "+v"(q[6]), "+v"(q[7]),
                           "+v"(t[0]), "+v"(t[1]), "+v"(t[2]), "+v"(t[3]),
                           "+v"(t[4]), "+v"(t[5]), "+v"(t[6]), "+v"(t[7]));
            __builtin_amdgcn_sched_barrier(0);

            #pragma unroll
            for (int c = 0; c < 8; ++c) {
                int i = (c >> 2) & 1, j = (c >> 1) & 1, k = c & 1;
                float wi = p0[i], wj = p1[j], wk = p2[k];
                float si = i ? 1.f : -1.f;
                float sj = j ? 1.f : -1.f;
                float sk = k ? 1.f : -1.f;
                float w   = wi * wj * wk;
                float dwx = si * wj * wk;
                float dwy = wi * sj * wk;
                float dwz = wi * wj * sk;
                float vv[5] = {q[c][0], q[c][1], q[c][2], q[c][3], t[c]};
                #pragma unroll
                for (int f = 0; f < 5; ++f) {
                    float v = vv[f];
                    accf[f] += w   * v;
                    adx[f]  += dwx * v;
                    ady[f]  += dwy * v;
                    adz[f]  += dwz * v;
                }
            }
        }
    }

    // ---- stage outputs into LDS (odd strides 5/15 -> near-conflict-free) ----
    if (tid < cnt) {
        float* fs = smem + tid * 5;
        #pragma unroll
        for (int f = 0; f < 5; ++f) fs[f] = accf[f];
        float* ds = smem + 1280 + tid * 15;
        #pragma unroll
        for (int f = 0; f < 5; ++f) {
            ds[f*3+0] = adx[f] * 100.0f;
            ds[f*3+1] = ady[f] * 100.0f;
            ds[f*3+2] = adz[f] * 100.0f;
        }
        // mask: direct coalesced dword store (no staging needed)
        out[(size_t)NPTS * 20 + base + tid] = mval;
    }
    __syncthreads();

    // ---- coalesced float4 global writes ----
    {
        const float4* s4 = (const float4*)smem;
        float4* o = (float4*)(out + (size_t)base * 5);
        int nf4 = (cnt * 5) >> 2;             // 320 or 160
        for (int i = tid; i < nf4; i += BLK) o[i] = s4[i];
    }
    {
        const float4* s4 = (const float4*)(smem + 1280);
        float4* o = (float4*)(out + (size_t)NPTS * 5 + (size_t)base * 15);
        int nf4 = (cnt * 15) >> 2;            // 960 or 480
        for (int i = tid; i < nf4; i += BLK) o[i] = s4[i];
    }
}

extern "C" void kernel_launch(void* const* d_in, const int* in_sizes, int n_in,
                              void* d_out, int out_size, void* d_ws, size_t ws_size,
                              hipStream_t stream) {
    const float* x    = (const float*)d_in[0];
    const float* feat = (const float*)d_in[1];
    const int*   btab = (const int*)d_in[2];
    float* out = (float*)d_out;
    int blocks = (NPTS + BLK - 1) / BLK;      // 7813
    hashgrid_kernel<<<blocks, BLK, 0, stream>>>(x, feat, btab, out);
}

// Round 6
// 410.271 us; speedup vs baseline: 1.1831x; 1.0629x over previous
//
#include <hip/hip_runtime.h>
#include <math.h>

#define NPTS 2000000
#define GG 32
#define FF 5
#define BLK 256

typedef float v4f __attribute__((ext_vector_type(4)));
typedef float v2f __attribute__((ext_vector_type(2)));

// r3 post-mortem: forcing a 16-deep load pipeline bought only +3% -> NOT
// latency-bound. ~48M divergent line-requests / 477K cy = ~12.5 req/cy per
// XCD-L2 ~ the L2 request-service ceiling. This round cuts requests/point
// from ~24 to ~16:
//   - btab: 1 load when no dim crosses a block boundary (67% of points)
//   - feat: z-adjacent corner rows are contiguous 40B when (xi2&7)!=7
//           (7/8 of points) -> 3 loads per row-pair instead of 4.
// FP accumulation order (c=0..7) is preserved -> bit-identical results.
// r4/r5: container-level failures (no compile log, no pytest verdict).
// Hardening: all asm load outputs are now early-clobber "=&v" so a dest
// can never alias a live address pair (the only kernel-attributable
// failure mechanism the audits surfaced). Logic unchanged.
__global__ __launch_bounds__(256) void hashgrid_kernel(
    const float* __restrict__ x,
    const float* __restrict__ feat,
    const int* __restrict__ btab,
    float* __restrict__ out)
{
    // staging: [0,1280) feats | [1280,5120) dfeats
    // (region [0,768) first reused to stage x coalesced)
    // mask stored direct (coalesced dword). LDS = 20480 B.
    __shared__ float smem[5120];
    const int tid  = threadIdx.x;
    const int bid  = blockIdx.x;
    const int base = bid * BLK;
    const int cnt  = min(BLK, NPTS - base);   // 256, or 128 for the last block

    // ---- stage x (coalesced float4) ----
    {
        const float4* xin = (const float4*)(x + (size_t)base * 3);
        float4* s4 = (float4*)smem;
        int nf4 = (cnt * 3) >> 2;             // 192 or 96
        for (int i = tid; i < nf4; i += BLK) s4[i] = xin[i];
    }
    __syncthreads();

    float x0 = 0.f, x1 = 0.f, x2 = 0.f;
    if (tid < cnt) { x0 = smem[tid*3+0]; x1 = smem[tid*3+1]; x2 = smem[tid*3+2]; }
    __syncthreads();   // smem reused for outputs below

    float accf[5] = {0,0,0,0,0};
    float adx[5]  = {0,0,0,0,0};
    float ady[5]  = {0,0,0,0,0};
    float adz[5]  = {0,0,0,0,0};
    float mval = 0.f;

    if (tid < cnt) {
        // reference semantics: u = fl32(x * 100.0f), floor/frac in f32
        float u0 = x0 * 100.0f, u1 = x1 * 100.0f, u2 = x2 * 100.0f;
        float fl0 = floorf(u0), fl1 = floorf(u1), fl2 = floorf(u2);
        int xi0 = (int)fl0, xi1 = (int)fl1, xi2 = (int)fl2;
        float fr0 = u0 - fl0, fr1 = u1 - fl1, fr2 = u2 - fl2;

        int vidx[8];
        #pragma unroll
        for (int c = 0; c < 8; ++c) {
            int i = (c >> 2) & 1, j = (c >> 1) & 1, k = c & 1;
            vidx[c] = (((xi0 + i) & 7) * 8 + ((xi1 + j) & 7)) * 8 + ((xi2 + k) & 7);
        }

        const bool cz = (xi2 & 7) == 7;
        const bool anycross = ((xi0 & 7) == 7) | ((xi1 & 7) == 7) | cz;

        int offs[8];
        bool ok;
        if (!anycross) {
            // all 8 corners in one block; xi in [0,255] -> block in [0,31], inb true
            const int* bp = btab + (((xi0 >> 3) * GG + (xi1 >> 3)) * GG + (xi2 >> 3));
            int bv;
            asm volatile("global_load_dword %0, %1, off" : "=&v"(bv) : "v"(bp));
            asm volatile("s_waitcnt vmcnt(0)" : "+v"(bv));
            __builtin_amdgcn_sched_barrier(0);
            ok = bv >= 0;
            int bo = max(bv, 0) * 520;
            #pragma unroll
            for (int c = 0; c < 8; ++c) offs[c] = bo + vidx[c];
        } else {
            // generic path (r3): 8 parallel btab gathers, exec-masked to
            // crossing lanes only -> ~1/3 of lanes issue these
            bool inb[8]; int bv[8];
            #pragma unroll
            for (int c = 0; c < 8; ++c) {
                int i = (c >> 2) & 1, j = (c >> 1) & 1, k = c & 1;
                int g0 = xi0 + i, g1 = xi1 + j, g2 = xi2 + k;
                int b0 = g0 >> 3, b1 = g1 >> 3, b2 = g2 >> 3;
                inb[c] = ((unsigned)b0 < GG) & ((unsigned)b1 < GG) & ((unsigned)b2 < GG);
                int c0 = min(max(b0,0),GG-1), c1 = min(max(b1,0),GG-1), c2 = min(max(b2,0),GG-1);
                const int* bp = btab + ((c0 * GG + c1) * GG + c2);
                asm volatile("global_load_dword %0, %1, off"
                             : "=&v"(bv[c]) : "v"(bp));
            }
            asm volatile("s_waitcnt vmcnt(0)"
                         : "+v"(bv[0]), "+v"(bv[1]), "+v"(bv[2]), "+v"(bv[3]),
                           "+v"(bv[4]), "+v"(bv[5]), "+v"(bv[6]), "+v"(bv[7]));
            __builtin_amdgcn_sched_barrier(0);
            ok = true;
            #pragma unroll
            for (int c = 0; c < 8; ++c) {
                ok &= inb[c] & (bv[c] >= 0);
                offs[c] = max(bv[c], 0) * 520 + vidx[c];
            }
        }

        if (ok) {
            mval = 1.f;
            float p0[2] = {1.f - fr0, fr0};
            float p1[2] = {1.f - fr1, fr1};
            float p2[2] = {1.f - fr2, fr2};

            if (!cz) {
                // z-pairs contiguous: rows offs[2p], offs[2p]+1 span 40 B.
                // 3 requests per pair (x4, x4@16, x2@32) instead of 4.
                v4f A[4], B[4]; v2f C[4];
                #pragma unroll
                for (int p = 0; p < 4; ++p) {
                    const float* fp = feat + (size_t)offs[p*2] * 5;
                    asm volatile("global_load_dwordx4 %0, %1, off"
                                 : "=&v"(A[p]) : "v"(fp));
                    asm volatile("global_load_dwordx4 %0, %1, off offset:16"
                                 : "=&v"(B[p]) : "v"(fp));
                    asm volatile("global_load_dwordx2 %0, %1, off offset:32"
                                 : "=&v"(C[p]) : "v"(fp));
                }
                asm volatile("s_waitcnt vmcnt(0)"
                             : "+v"(A[0]), "+v"(A[1]), "+v"(A[2]), "+v"(A[3]),
                               "+v"(B[0]), "+v"(B[1]), "+v"(B[2]), "+v"(B[3]),
                               "+v"(C[0]), "+v"(C[1]), "+v"(C[2]), "+v"(C[3]));
                __builtin_amdgcn_sched_barrier(0);

                #pragma unroll
                for (int p = 0; p < 4; ++p) {
                    int i = (p >> 1) & 1, j = p & 1;
                    float wi = p0[i], wj = p1[j];
                    float si = i ? 1.f : -1.f;
                    float sj = j ? 1.f : -1.f;
                    float wij = wi * wj;
                    float dxy = si * wj;     // dwx / wk
                    float dyx = wi * sj;     // dwy / wk
                    // corner c=2p (k=0): row = {A.x,A.y,A.z,A.w,B.x}
                    {
                        float wk = p2[0];
                        float w = wij * wk, dwx = dxy * wk, dwy = dyx * wk, dwz = -wij;
                        float vv[5] = {A[p][0], A[p][1], A[p][2], A[p][3], B[p][0]};
                        #pragma unroll
                        for (int f = 0; f < 5; ++f) {
                            float v = vv[f];
                            accf[f] += w   * v;
                            adx[f]  += dwx * v;
                            ady[f]  += dwy * v;
                            adz[f]  += dwz * v;
                        }
                    }
                    // corner c=2p+1 (k=1): row = {B.y,B.z,B.w,C.x,C.y}
                    {
                        float wk = p2[1];
                        float w = wij * wk, dwx = dxy * wk, dwy = dyx * wk, dwz = wij;
                        float vv[5] = {B[p][1], B[p][2], B[p][3], C[p][0], C[p][1]};
                        #pragma unroll
                        for (int f = 0; f < 5; ++f) {
                            float v = vv[f];
                            accf[f] += w   * v;
                            adx[f]  += dwx * v;
                            ady[f]  += dwy * v;
                            adz[f]  += dwz * v;
                        }
                    }
                }
            } else {
                // generic path (r3): 16 parallel feat gathers
                v4f q[8]; float t[8];
                #pragma unroll
                for (int c = 0; c < 8; ++c) {
                    const float* fp = feat + (size_t)offs[c] * 5;
                    asm volatile("global_load_dwordx4 %0, %1, off"
                                 : "=&v"(q[c]) : "v"(fp));
                    asm volatile("global_load_dword %0, %1, off offset:16"
                                 : "=&v"(t[c]) : "v"(fp));
                }
                asm volatile("s_waitcnt vmcnt(0)"
                             : "+v"(q[0]), "+v"(q[1]), "+v"(q[2]), "+v"(q[3]),
                               "+v"(q[4]), "+v"(q[5]), "+v"(q[6]), "+v"(q[7]),
                               "+v"(t[0]), "+v"(t[1]), "+v"(t[2]), "+v"(t[3]),
                               "+v"(t[4]), "+v"(t[5]), "+v"(t[6]), "+v"(t[7]));
                __builtin_amdgcn_sched_barrier(0);

                #pragma unroll
                for (int c = 0; c < 8; ++c) {
                    int i = (c >> 2) & 1, j = (c >> 1) & 1, k = c & 1;
                    float wi = p0[i], wj = p1[j], wk = p2[k];
                    float si = i ? 1.f : -1.f;
                    float sj = j ? 1.f : -1.f;
                    float sk = k ? 1.f : -1.f;
                    float w   = wi * wj * wk;
                    float dwx = si * wj * wk;
                    float dwy = wi * sj * wk;
                    float dwz = wi * wj * sk;
                    float vv[5] = {q[c][0], q[c][1], q[c][2], q[c][3], t[c]};
                    #pragma unroll
                    for (int f = 0; f < 5; ++f) {
                        float v = vv[f];
                        accf[f] += w   * v;
                        adx[f]  += dwx * v;
                        ady[f]  += dwy * v;
                        adz[f]  += dwz * v;
                    }
                }
            }
        }
    }

    // ---- stage outputs into LDS (odd strides 5/15 -> near-conflict-free) ----
    if (tid < cnt) {
        float* fs = smem + tid * 5;
        #pragma unroll
        for (int f = 0; f < 5; ++f) fs[f] = accf[f];
        float* ds = smem + 1280 + tid * 15;
        #pragma unroll
        for (int f = 0; f < 5; ++f) {
            ds[f*3+0] = adx[f] * 100.0f;
            ds[f*3+1] = ady[f] * 100.0f;
            ds[f*3+2] = adz[f] * 100.0f;
        }
        // mask: direct coalesced dword store (no staging needed)
        out[(size_t)NPTS * 20 + base + tid] = mval;
    }
    __syncthreads();

    // ---- coalesced float4 global writes ----
    {
        const float4* s4 = (const float4*)smem;
        float4* o = (float4*)(out + (size_t)base * 5);
        int nf4 = (cnt * 5) >> 2;             // 320 or 160
        for (int i = tid; i < nf4; i += BLK) o[i] = s4[i];
    }
    {
        const float4* s4 = (const float4*)(smem + 1280);
        float4* o = (float4*)(out + (size_t)NPTS * 5 + (size_t)base * 15);
        int nf4 = (cnt * 15) >> 2;            // 960 or 480
        for (int i = tid; i < nf4; i += BLK) o[i] = s4[i];
    }
}

extern "C" void kernel_launch(void* const* d_in, const int* in_sizes, int n_in,
                              void* d_out, int out_size, void* d_ws, size_t ws_size,
                              hipStream_t stream) {
    const float* x    = (const float*)d_in[0];
    const float* feat = (const float*)d_in[1];
    const int*   btab = (const int*)d_in[2];
    float* out = (float*)d_out;
    int blocks = (NPTS + BLK - 1) / BLK;      // 7813
    hashgrid_kernel<<<blocks, BLK, 0, stream>>>(x, feat, btab, out);
}

// Round 7
// 399.283 us; speedup vs baseline: 1.2156x; 1.0275x over previous
//
#include <hip/hip_runtime.h>
#include <math.h>

#define NPTS 2000000
#define GG 32
#define FF 5
#define BLK 256

typedef float v4f __attribute__((ext_vector_type(4)));
typedef float v2f __attribute__((ext_vector_type(2)));

// r6 post-mortem: T = a*requests + b with b~85us of request-independent time,
// partly the 4 serial vmcnt(0) round-trips per wave the r6 branch structure
// created. r7: (1) one RT for btab via issue-all-paths-then-wait (and a new
// 2-load path for the 87% of crossing points that cross exactly one dim:
// avg btab req 3.3 -> ~1.6); (2) one RT for feat (pair + generic issued
// back-to-back, first consume branch's wait drains both). Waits are tied
// only to their own path's regs (no uninitialized-reg UB); sched_barrier(0)
// after each wait per rule-18. Accumulation order c=0..7 preserved ->
// bit-identical to r6.
__global__ __launch_bounds__(256) void hashgrid_kernel(
    const float* __restrict__ x,
    const float* __restrict__ feat,
    const int* __restrict__ btab,
    float* __restrict__ out)
{
    // staging: [0,1280) feats | [1280,5120) dfeats
    // (region [0,768) first reused to stage x coalesced)
    // mask stored direct (coalesced dword). LDS = 20480 B.
    __shared__ float smem[5120];
    const int tid  = threadIdx.x;
    const int bid  = blockIdx.x;
    const int base = bid * BLK;
    const int cnt  = min(BLK, NPTS - base);   // 256, or 128 for the last block

    // ---- stage x (coalesced float4) ----
    {
        const float4* xin = (const float4*)(x + (size_t)base * 3);
        float4* s4 = (float4*)smem;
        int nf4 = (cnt * 3) >> 2;             // 192 or 96
        for (int i = tid; i < nf4; i += BLK) s4[i] = xin[i];
    }
    __syncthreads();

    float x0 = 0.f, x1 = 0.f, x2 = 0.f;
    if (tid < cnt) { x0 = smem[tid*3+0]; x1 = smem[tid*3+1]; x2 = smem[tid*3+2]; }
    __syncthreads();   // smem reused for outputs below

    float accf[5] = {0,0,0,0,0};
    float adx[5]  = {0,0,0,0,0};
    float ady[5]  = {0,0,0,0,0};
    float adz[5]  = {0,0,0,0,0};
    float mval = 0.f;

    if (tid < cnt) {
        // reference semantics: u = fl32(x * 100.0f), floor/frac in f32
        float u0 = x0 * 100.0f, u1 = x1 * 100.0f, u2 = x2 * 100.0f;
        float fl0 = floorf(u0), fl1 = floorf(u1), fl2 = floorf(u2);
        int xi0 = (int)fl0, xi1 = (int)fl1, xi2 = (int)fl2;
        float fr0 = u0 - fl0, fr1 = u1 - fl1, fr2 = u2 - fl2;

        int vidx[8];
        #pragma unroll
        for (int c = 0; c < 8; ++c) {
            int i = (c >> 2) & 1, j = (c >> 1) & 1, k = c & 1;
            vidx[c] = (((xi0 + i) & 7) * 8 + ((xi1 + j) & 7)) * 8 + ((xi2 + k) & 7);
        }

        const bool fx = (xi0 & 7) == 7;
        const bool fy = (xi1 & 7) == 7;
        const bool cz = (xi2 & 7) == 7;
        const int ncross = (int)fx + (int)fy + (int)cz;
        const int blo = ((xi0 >> 3) * GG + (xi1 >> 3)) * GG + (xi2 >> 3); // always in-grid

        // ---- btab: issue all three exec-masked variants, then ONE wait ----
        int bv0, bv1, bvm[8];
        int dsel = 0; bool hi_ok = true; bool inb[8];
        if (ncross == 0) {
            // all 8 corners in one block
            asm volatile("global_load_dword %0, %1, off"
                         : "=&v"(bv0) : "v"(btab + blo));
        } else if (ncross == 1) {
            // exactly one dim crosses: only 2 distinct blocks among 8 corners
            dsel       = fx ? 4 : (fy ? 2 : 1);                  // corner-bit of crossed dim
            int stride = fx ? GG * GG : (fy ? GG : 1);
            int bcoord = fx ? (xi0 >> 3) : (fy ? (xi1 >> 3) : (xi2 >> 3));
            hi_ok      = (bcoord + 1) < GG;                      // else out-of-grid -> ok=false
            asm volatile("global_load_dword %0, %1, off"
                         : "=&v"(bv0) : "v"(btab + blo));
            asm volatile("global_load_dword %0, %1, off"
                         : "=&v"(bv1) : "v"(btab + blo + (hi_ok ? stride : 0)));
        } else {
            // generic: 8 loads
            #pragma unroll
            for (int c = 0; c < 8; ++c) {
                int i = (c >> 2) & 1, j = (c >> 1) & 1, k = c & 1;
                int g0 = xi0 + i, g1 = xi1 + j, g2 = xi2 + k;
                int b0 = g0 >> 3, b1 = g1 >> 3, b2 = g2 >> 3;
                inb[c] = ((unsigned)b0 < GG) & ((unsigned)b1 < GG) & ((unsigned)b2 < GG);
                int c0 = min(max(b0,0),GG-1), c1 = min(max(b1,0),GG-1), c2 = min(max(b2,0),GG-1);
                asm volatile("global_load_dword %0, %1, off"
                             : "=&v"(bvm[c]) : "v"(btab + ((c0 * GG + c1) * GG + c2)));
            }
        }

        // consume: the FIRST branch executed by the wave drains all btab loads
        // (vmcnt is wave-level); each wait ties only its own path's regs.
        bool ok = false;
        int offs[8];
        if (ncross == 0) {
            asm volatile("s_waitcnt vmcnt(0)" : "+v"(bv0));
            __builtin_amdgcn_sched_barrier(0);
            ok = bv0 >= 0;
            int bo = max(bv0, 0) * 520;
            #pragma unroll
            for (int c = 0; c < 8; ++c) offs[c] = bo + vidx[c];
        } else if (ncross == 1) {
            asm volatile("s_waitcnt vmcnt(0)" : "+v"(bv0), "+v"(bv1));
            __builtin_amdgcn_sched_barrier(0);
            ok = hi_ok & (bv0 >= 0) & (bv1 >= 0);
            int blo_s = max(bv0, 0) * 520;
            int bhi_s = max(bv1, 0) * 520;
            #pragma unroll
            for (int c = 0; c < 8; ++c)
                offs[c] = ((c & dsel) ? bhi_s : blo_s) + vidx[c];
        } else {
            asm volatile("s_waitcnt vmcnt(0)"
                         : "+v"(bvm[0]), "+v"(bvm[1]), "+v"(bvm[2]), "+v"(bvm[3]),
                           "+v"(bvm[4]), "+v"(bvm[5]), "+v"(bvm[6]), "+v"(bvm[7]));
            __builtin_amdgcn_sched_barrier(0);
            ok = true;
            #pragma unroll
            for (int c = 0; c < 8; ++c) {
                ok &= inb[c] & (bvm[c] >= 0);
                offs[c] = max(bvm[c], 0) * 520 + vidx[c];
            }
        }

        if (ok) {
            mval = 1.f;
            float p0[2] = {1.f - fr0, fr0};
            float p1[2] = {1.f - fr1, fr1};
            float p2[2] = {1.f - fr2, fr2};

            // ---- feat: issue BOTH variants (exec-masked), then one RT ----
            v4f A[4], B[4]; v2f C[4];   // pair path (!cz): 12 loads
            v4f q[8]; float t[8];       // generic path (cz): 16 loads
            if (!cz) {
                // z-pairs contiguous: rows offs[2p], offs[2p]+1 span 40 B.
                #pragma unroll
                for (int p = 0; p < 4; ++p) {
                    const float* fp = feat + (size_t)offs[p*2] * 5;
                    asm volatile("global_load_dwordx4 %0, %1, off"
                                 : "=&v"(A[p]) : "v"(fp));
                    asm volatile("global_load_dwordx4 %0, %1, off offset:16"
                                 : "=&v"(B[p]) : "v"(fp));
                    asm volatile("global_load_dwordx2 %0, %1, off offset:32"
                                 : "=&v"(C[p]) : "v"(fp));
                }
            } else {
                #pragma unroll
                for (int c = 0; c < 8; ++c) {
                    const float* fp = feat + (size_t)offs[c] * 5;
                    asm volatile("global_load_dwordx4 %0, %1, off"
                                 : "=&v"(q[c]) : "v"(fp));
                    asm volatile("global_load_dword %0, %1, off offset:16"
                                 : "=&v"(t[c]) : "v"(fp));
                }
            }

            if (!cz) {
                asm volatile("s_waitcnt vmcnt(0)"
                             : "+v"(A[0]), "+v"(A[1]), "+v"(A[2]), "+v"(A[3]),
                               "+v"(B[0]), "+v"(B[1]), "+v"(B[2]), "+v"(B[3]),
                               "+v"(C[0]), "+v"(C[1]), "+v"(C[2]), "+v"(C[3]));
                __builtin_amdgcn_sched_barrier(0);
                #pragma unroll
                for (int p = 0; p < 4; ++p) {
                    int i = (p >> 1) & 1, j = p & 1;
                    float wi = p0[i], wj = p1[j];
                    float si = i ? 1.f : -1.f;
                    float sj = j ? 1.f : -1.f;
                    float wij = wi * wj;
                    float dxy = si * wj;     // dwx / wk
                    float dyx = wi * sj;     // dwy / wk
                    // corner c=2p (k=0): row = {A.x,A.y,A.z,A.w,B.x}
                    {
                        float wk = p2[0];
                        float w = wij * wk, dwx = dxy * wk, dwy = dyx * wk, dwz = -wij;
                        float vv[5] = {A[p][0], A[p][1], A[p][2], A[p][3], B[p][0]};
                        #pragma unroll
                        for (int f = 0; f < 5; ++f) {
                            float v = vv[f];
                            accf[f] += w   * v;
                            adx[f]  += dwx * v;
                            ady[f]  += dwy * v;
                            adz[f]  += dwz * v;
                        }
                    }
                    // corner c=2p+1 (k=1): row = {B.y,B.z,B.w,C.x,C.y}
                    {
                        float wk = p2[1];
                        float w = wij * wk, dwx = dxy * wk, dwy = dyx * wk, dwz = wij;
                        float vv[5] = {B[p][1], B[p][2], B[p][3], C[p][0], C[p][1]};
                        #pragma unroll
                        for (int f = 0; f < 5; ++f) {
                            float v = vv[f];
                            accf[f] += w   * v;
                            adx[f]  += dwx * v;
                            ady[f]  += dwy * v;
                            adz[f]  += dwz * v;
                        }
                    }
                }
            } else {
                asm volatile("s_waitcnt vmcnt(0)"
                             : "+v"(q[0]), "+v"(q[1]), "+v"(q[2]), "+v"(q[3]),
                               "+v"(q[4]), "+v"(q[5]), "+v"(q[6]), "+v"(q[7]),
                               "+v"(t[0]), "+v"(t[1]), "+v"(t[2]), "+v"(t[3]),
                               "+v"(t[4]), "+v"(t[5]), "+v"(t[6]), "+v"(t[7]));
                __builtin_amdgcn_sched_barrier(0);
                #pragma unroll
                for (int c = 0; c < 8; ++c) {
                    int i = (c >> 2) & 1, j = (c >> 1) & 1, k = c & 1;
                    float wi = p0[i], wj = p1[j], wk = p2[k];
                    float si = i ? 1.f : -1.f;
                    float sj = j ? 1.f : -1.f;
                    float sk = k ? 1.f : -1.f;
                    float w   = wi * wj * wk;
                    float dwx = si * wj * wk;
                    float dwy = wi * sj * wk;
                    float dwz = wi * wj * sk;
                    float vv[5] = {q[c][0], q[c][1], q[c][2], q[c][3], t[c]};
                    #pragma unroll
                    for (int f = 0; f < 5; ++f) {
                        float v = vv[f];
                        accf[f] += w   * v;
                        adx[f]  += dwx * v;
                        ady[f]  += dwy * v;
                        adz[f]  += dwz * v;
                    }
                }
            }
        }
    }

    // ---- stage outputs into LDS (odd strides 5/15 -> near-conflict-free) ----
    if (tid < cnt) {
        float* fs = smem + tid * 5;
        #pragma unroll
        for (int f = 0; f < 5; ++f) fs[f] = accf[f];
        float* ds = smem + 1280 + tid * 15;
        #pragma unroll
        for (int f = 0; f < 5; ++f) {
            ds[f*3+0] = adx[f] * 100.0f;
            ds[f*3+1] = ady[f] * 100.0f;
            ds[f*3+2] = adz[f] * 100.0f;
        }
        // mask: direct coalesced dword store (no staging needed)
        out[(size_t)NPTS * 20 + base + tid] = mval;
    }
    __syncthreads();

    // ---- coalesced float4 global writes ----
    {
        const float4* s4 = (const float4*)smem;
        float4* o = (float4*)(out + (size_t)base * 5);
        int nf4 = (cnt * 5) >> 2;             // 320 or 160
        for (int i = tid; i < nf4; i += BLK) o[i] = s4[i];
    }
    {
        const float4* s4 = (const float4*)(smem + 1280);
        float4* o = (float4*)(out + (size_t)NPTS * 5 + (size_t)base * 15);
        int nf4 = (cnt * 15) >> 2;            // 960 or 480
        for (int i = tid; i < nf4; i += BLK) o[i] = s4[i];
    }
}

extern "C" void kernel_launch(void* const* d_in, const int* in_sizes, int n_in,
                              void* d_out, int out_size, void* d_ws, size_t ws_size,
                              hipStream_t stream) {
    const float* x    = (const float*)d_in[0];
    const float* feat = (const float*)d_in[1];
    const int*   btab = (const int*)d_in[2];
    float* out = (float*)d_out;
    int blocks = (NPTS + BLK - 1) / BLK;      // 7813
    hashgrid_kernel<<<blocks, BLK, 0, stream>>>(x, feat, btab, out);
}